// Round 13
// baseline (314.772 us; speedup 1.0000x reference)
//
#include <hip/hip_runtime.h>
#include <hip/hip_bf16.h>
#include <cfloat>

// VQ-VAE vector quantizer.  N=262144 rows x D=100, K=512 codes.
// out[0..N*D-1] = quantized (fp32-exact gather); out[N*D]=mse; out[N*D+1]=0.25*mse.
//
// R18: R14 (best, 86us) with wave-private LDS double buffers -- ZERO main-loop
//  barriers.  Post-mortem R15/R16/R17: LDS-pipe cut, instruction cut, and
//  MFMA-chain interleave all failed to beat R14 (91 vs 86); R17's null result
//  killed the dependent-latency theory.  R14's profile: 38% issue-busy, 62%
//  idle at 1.6 waves/SIMD; per-block critical path ~35us vs ~10K issued
//  cycles.  The only un-isolated per-round serializer on the R14 structure is
//  the block-wide round join {vmcnt(0) drain -> ds_write -> __syncthreads ->
//  4-wave re-align}, calibrated at ~0.5us/round by R5->R11 (16->8 rounds).
//  R18 removes it without touching the B-path:
//   - each wave owns 2 x 8KB LDS buffers (4 waves x 16KB = 64KB/block)
//   - per round: 8 coalesced uint4 L2 loads of the next chunk (cb is L2-hot;
//     4x re-read = 512MB aggregate L2 traffic, absorbed), ds_write to the idle
//     private buffer, ds_read+MFMA+fold from the live one -- all same-wave
//     deps, compiler-inserted waitcnt only, NO __syncthreads until the single
//     pre-epilogue widx join.
//   - B-fragment reads, MFMA order, fold, tie-break, epilogue: R14 exact.
//  Tripwires: WRITE exactly 102432 (spill; VGPR est 120-150); conflicts 0;
//  absmax <= 0.00390625.  Occupancy may DROP to ~13-16% (64KB LDS -> 2
//  blocks/CU): irrelevant per established law (occupancy never converted).
//  Falsifier: dur >= 86us -> round join was never the stall -> revert to R14
//  and declare the practical floor.
//
// ws: ws_f[0] = loss accum; ws_f[16..528) = e2[k] (fp32, reference);
//     bytes [4096..4096+131072): bf16 cb; chunk c granule layout (16B granules):
//     granule g = (s*2+tt)*64 + quad*16 + lr  holds code (c*32+tt*16+lr),
//     k = s*32+quad*8+{0..7}; k=100 slot holds bf16(-e2/2); other k>=101 zero.

#define N_ROWS (64 * 64 * 64)
#define D 100
#define KCODES 512
#define CB_OFF 4096
#define E2_OFF 16

typedef __attribute__((ext_vector_type(8))) short short8;
typedef __attribute__((ext_vector_type(4))) float f32x4;

__device__ __forceinline__ unsigned short f2bf(float f) {
    union { float f; unsigned u; } v; v.f = f;
    unsigned r = v.u + 0x7FFF + ((v.u >> 16) & 1);   // RNE
    return (unsigned short)(r >> 16);
}
__device__ __forceinline__ unsigned pk2(float a, float b) {   // packed bf16 cvt (RNE)
    union { __hip_bfloat162 h; unsigned u; } c;
    c.h = __float22bfloat162_rn(make_float2(a, b));
    return c.u;
}
__device__ __forceinline__ short8 pack8(const float4& a, const float4& b) {
    union { unsigned u[4]; short8 v; } r;
    r.u[0] = pk2(a.x, a.y); r.u[1] = pk2(a.z, a.w);
    r.u[2] = pk2(b.x, b.y); r.u[3] = pk2(b.z, b.w);
    return r.v;
}
__device__ __forceinline__ unsigned f2u(float f) {
    union { float f; unsigned u; } v; v.f = f; return v.u;
}
__device__ __forceinline__ float u2f(unsigned u) {
    union { unsigned u; float f; } v; v.u = u; return v.f;
}

// ---- init: one wave per code (R14 layout) ----
__global__ __launch_bounds__(64) void vq_init(const float* __restrict__ emb,
                                              float* __restrict__ ws) {
    const int code = blockIdx.x, l = threadIdx.x;
    const float* e = emb + code * D;
    if (code == 0 && l == 0) ws[0] = 0.0f;
    float a = e[l];
    float b = (l < D - 64) ? e[64 + l] : 0.0f;
    float p = fmaf(a, a, b * b);
#pragma unroll
    for (int off = 32; off; off >>= 1) p += __shfl_xor(p, off);   // all lanes: e2
    if (l == 0) ws[E2_OFF + code] = p;

    // cb granules: 16 per code, written by lanes 0..15 (8 shorts each)
    if (l < 16) {
        const int s = l >> 2, q = l & 3;
        short8 v;
#pragma unroll
        for (int j = 0; j < 8; ++j) {
            int k = s * 32 + q * 8 + j;
            v[j] = (k < D) ? (short)f2bf(e[k]) : (short)0;
        }
        if (l == 12) v[4] = (short)f2bf(-0.5f * p);   // k=100 slot: -e2/2
        const int chunk = code >> 5, ci = code & 31;
        const int tt = ci >> 4, lr = ci & 15;
        unsigned short* cb = (unsigned short*)((char*)ws + CB_OFF);
        // short offset = chunk*4096 + granule*8, granule = (s*2+tt)*64 + q*16 + lr
        *(short8*)(cb + chunk * 4096 + ((s * 2 + tt) * 64 + q * 16 + lr) * 8) = v;
    }
}

// ---- main: 4 waves/block, 64 rows/wave (M=4), wave-private LDS dbuf ----
__global__ __launch_bounds__(256, 2) void vq_main(const float* __restrict__ x,
                                                  const float* __restrict__ emb,
                                                  float* __restrict__ ws,
                                                  float* __restrict__ out) {
    __shared__ uint4  pbuf[2][4][512];   // [buf][wave][granule]: 64 KB private
    __shared__ int    widx[256];
    __shared__ float  wsum[4];

    const int tid = threadIdx.x, wave = tid >> 6, lane = tid & 63;
    const int quad = lane >> 4, lr = lane & 15;
    const int lrc = 15 - lr;                          // code-complement lane part
    const long brow = (long)blockIdx.x * 256;
    const long wrow = brow + wave * 64;

    // ---- A: 28 independent scattered loads (batched), then convert ----
    float4 av[4][7];
#pragma unroll
    for (int m = 0; m < 4; ++m) {
        const float* xr = x + (wrow + m * 16 + lr) * D + quad * 8;
        av[m][0] = *(const float4*)(xr);
        av[m][1] = *(const float4*)(xr + 4);
        av[m][2] = *(const float4*)(xr + 32);
        av[m][3] = *(const float4*)(xr + 36);
        av[m][4] = *(const float4*)(xr + 64);
        av[m][5] = *(const float4*)(xr + 68);
        av[m][6] = *(const float4*)(x + (wrow + m * 16 + lr) * D + 96);  // same addr all quads
    }

    // ---- chunk 0 private staging (8 coalesced loads; in flight with A) ----
    const uint4* __restrict__ cbg = (const uint4*)((const char*)ws + CB_OFF);
    uint4 st[8];
#pragma unroll
    for (int k = 0; k < 8; ++k) st[k] = cbg[k * 64 + lane];

    // ---- convert A -> fragments + fp32 norms; k=100 carries 1.0 (quad 0) ----
    short8 A[4][4];
    float  xnorm[4];
    const float4 one0 = make_float4(quad == 0 ? 1.f : 0.f, 0.f, 0.f, 0.f);
#pragma unroll
    for (int m = 0; m < 4; ++m) {
        float4 z = av[m][6];
        if (quad != 0) z = make_float4(0.f, 0.f, 0.f, 0.f);   // tail only in quad 0
        float nrm = 0.f;
#pragma unroll
        for (int i = 0; i < 6; ++i) {
            float4 f = av[m][i];
            nrm = fmaf(f.x, f.x, nrm); nrm = fmaf(f.y, f.y, nrm);
            nrm = fmaf(f.z, f.z, nrm); nrm = fmaf(f.w, f.w, nrm);
        }
        nrm = fmaf(z.x, z.x, nrm); nrm = fmaf(z.y, z.y, nrm);
        nrm = fmaf(z.z, z.z, nrm); nrm = fmaf(z.w, z.w, nrm);
        A[m][0] = pack8(av[m][0], av[m][1]);
        A[m][1] = pack8(av[m][2], av[m][3]);
        A[m][2] = pack8(av[m][4], av[m][5]);
        A[m][3] = pack8(z, one0);                     // k=100 -> 1.0 (quad 0)
        nrm += __shfl_xor(nrm, 16);
        nrm += __shfl_xor(nrm, 32);
        xnorm[m] = nrm;
    }

    // write chunk 0 into this wave's buffer 0 (same-wave dep; no barrier)
#pragma unroll
    for (int k = 0; k < 8; ++k) pbuf[0][wave][k * 64 + lane] = st[k];

    // packed running max: acc with 9 LSBs = 511-code (argmax acc == argmin score)
    float runpk[4][4];
#pragma unroll
    for (int m = 0; m < 4; ++m)
#pragma unroll
        for (int r = 0; r < 4; ++r) runpk[m][r] = -FLT_MAX;

#pragma unroll 1
    for (int c = 0; c < 16; ++c) {
        const int p = c & 1;
        if (c < 15) {                     // prefetch next chunk into regs (private)
#pragma unroll
            for (int k = 0; k < 8; ++k) st[k] = cbg[(c + 1) * 512 + k * 64 + lane];
        }

        // B fragments: lane-linear ds_read_b128 from private buffer, conflict-free
        const short8* __restrict__ bl = (const short8*)&pbuf[p][wave][0];
        short8 B[2][4];
#pragma unroll
        for (int s = 0; s < 4; ++s) {
            B[0][s] = bl[(s * 2 + 0) * 64 + lane];
            B[1][s] = bl[(s * 2 + 1) * 64 + lane];
        }

        f32x4 acc[4][2];
#pragma unroll
        for (int m = 0; m < 4; ++m) {
            acc[m][0] = (f32x4){0.f, 0.f, 0.f, 0.f};
            acc[m][1] = (f32x4){0.f, 0.f, 0.f, 0.f};
        }
#pragma unroll
        for (int s = 0; s < 4; ++s)
#pragma unroll
            for (int m = 0; m < 4; ++m) {
                acc[m][0] = __builtin_amdgcn_mfma_f32_16x16x32_bf16(A[m][s], B[0][s], acc[m][0], 0, 0, 0);
                acc[m][1] = __builtin_amdgcn_mfma_f32_16x16x32_bf16(A[m][s], B[1][s], acc[m][1], 0, 0, 0);
            }

        // fold: pack (511-code) into 9 LSBs, running float max (v_and_or + max3)
        const int ib0 = (31 - (c * 2 + 0)) * 16 + lrc;
        const int ib1 = (31 - (c * 2 + 1)) * 16 + lrc;
#pragma unroll
        for (int m = 0; m < 4; ++m)
#pragma unroll
            for (int r = 0; r < 4; ++r) {
                float p0 = u2f((f2u(acc[m][0][r]) & ~511u) | (unsigned)ib0);
                float p1 = u2f((f2u(acc[m][1][r]) & ~511u) | (unsigned)ib1);
                runpk[m][r] = fmaxf(runpk[m][r], fmaxf(p0, p1));
            }

        if (c < 15) {                     // write next chunk to the idle buffer
#pragma unroll
            for (int k = 0; k < 8; ++k) pbuf[p ^ 1][wave][k * 64 + lane] = st[k];
        }
        // no __syncthreads: buffers are wave-private; compiler orders via lgkmcnt
    }

    // ---- per-row argmax across the 16 columns: pure float max-reduce ----
    float lsum = 0.0f;
#pragma unroll
    for (int m = 0; m < 4; ++m)
#pragma unroll
        for (int r = 0; r < 4; ++r) {
            float s = runpk[m][r];
#pragma unroll
            for (int off = 8; off >= 1; off >>= 1)
                s = fmaxf(s, __shfl_xor(s, off));
            if (lr == quad * 4 + r) {                  // writer lane for this row
                unsigned u = f2u(s);
                int code = 511 - (int)(u & 511u);
                lsum += fmaf(-2.0f, s, xnorm[m]);      // ||x||^2 - 2*(<x,e> - e2/2)
                widx[wave * 64 + m * 16 + quad * 4 + r] = code;
            }
        }
#pragma unroll
    for (int off = 32; off >= 1; off >>= 1) lsum += __shfl_xor(lsum, off);
    if (lane == 0) wsum[wave] = lsum;
    __syncthreads();                                   // the ONLY block join
    if (tid == 0) atomicAdd(ws, wsum[0] + wsum[1] + wsum[2] + wsum[3]);

    // ---- coalesced epilogue: 6400 float4 = 256 rows x 25, batched 5-deep ----
    const float4* __restrict__ ef = (const float4*)emb;   // 25 float4 per row, exact
    float4* __restrict__ og = (float4*)(out + brow * D);
#pragma unroll
    for (int i = 0; i < 25; i += 5) {
        float4 q[5];
        int    gi[5];
#pragma unroll
        for (int u = 0; u < 5; ++u) {
            int g = (i + u) * 256 + tid;
            int row = g / 25;                 // const-divisor magic div
            int c4  = g - row * 25;
            gi[u] = g;
            q[u]  = ef[(long)widx[row] * 25 + c4];
        }
#pragma unroll
        for (int u = 0; u < 5; ++u) og[gi[u]] = q[u];
    }
}

// ---- finalize ----
__global__ void vq_final(const float* __restrict__ ws, float* __restrict__ out) {
    float mse = ws[0] / (float)((long)N_ROWS * D);
    out[(long)N_ROWS * D]     = mse;
    out[(long)N_ROWS * D + 1] = 0.25f * mse;
}

extern "C" void kernel_launch(void* const* d_in, const int* in_sizes, int n_in,
                              void* d_out, int out_size, void* d_ws, size_t ws_size,
                              hipStream_t stream) {
    const float* x   = (const float*)d_in[0];
    const float* emb = (const float*)d_in[1];
    float* out = (float*)d_out;
    float* ws  = (float*)d_ws;

    vq_init<<<KCODES, 64, 0, stream>>>(emb, ws);
    vq_main<<<N_ROWS / 256, 256, 0, stream>>>(x, emb, ws, out);
    vq_final<<<1, 1, 0, stream>>>(ws, out);
}

// Round 14
// 239.116 us; speedup vs baseline: 1.3164x; 1.3164x over previous
//
#include <hip/hip_runtime.h>
#include <hip/hip_bf16.h>
#include <cfloat>

// VQ-VAE vector quantizer.  N=262144 rows x D=100, K=512 codes.
// out[0..N*D-1] = quantized (fp32-exact gather); out[N*D]=mse; out[N*D+1]=0.25*mse.
//
// R19: R14 (best, 86us) with 4-chunk staging rounds (4 barriers, was 8).
//  Post-mortem R18: wave-private LDS dbuf spilled (WRITE 238MB vs 102MB,
//  scratch) -- reverted.  13-round ledger: only two levers ever converted,
//  (1) issue-work cuts on the wave stream (R14 fold, -14us, 1:1) and
//  (2) barrier-round halving (R5->R11 16->8 rounds: -4us, ~0.5us/round).
//  R19 applies lever (2) once more to the R14 structure: 4 chunks/round,
//  2 x 32KB double buffers, 8 loads + 8 ds_writes per thread per round
//  (same totals), 4 __syncthreads instead of 8.  Math/fold/tie-break/
//  epilogue byte-identical to R14.
//  Tripwires: WRITE exactly 102432 (spill -- 32-VGPR prefetch batch is the
//  risk); VGPR 110-140 (not 64/88); conflicts 0; absmax <= 0.00390625.
//  Falsifier: dur >= 86us or spill -> revert to R14 verbatim, declare the
//  practical floor (no counter roofline; binding constraint is per-wave
//  issue/stall structure; remaining identified levers each <= 2%).
//
// ws: ws_f[0] = loss accum; ws_f[16..528) = e2[k] (fp32, reference);
//     bytes [4096..4096+131072): bf16 cb; chunk c granule layout (16B granules):
//     granule g = (s*2+tt)*64 + quad*16 + lr  holds code (c*32+tt*16+lr),
//     k = s*32+quad*8+{0..7}; k=100 slot holds bf16(-e2/2); other k>=101 zero.

#define N_ROWS (64 * 64 * 64)
#define D 100
#define KCODES 512
#define CB_OFF 4096
#define E2_OFF 16

typedef __attribute__((ext_vector_type(8))) short short8;
typedef __attribute__((ext_vector_type(4))) float f32x4;

__device__ __forceinline__ unsigned short f2bf(float f) {
    union { float f; unsigned u; } v; v.f = f;
    unsigned r = v.u + 0x7FFF + ((v.u >> 16) & 1);   // RNE
    return (unsigned short)(r >> 16);
}
__device__ __forceinline__ unsigned pk2(float a, float b) {   // packed bf16 cvt (RNE)
    union { __hip_bfloat162 h; unsigned u; } c;
    c.h = __float22bfloat162_rn(make_float2(a, b));
    return c.u;
}
__device__ __forceinline__ short8 pack8(const float4& a, const float4& b) {
    union { unsigned u[4]; short8 v; } r;
    r.u[0] = pk2(a.x, a.y); r.u[1] = pk2(a.z, a.w);
    r.u[2] = pk2(b.x, b.y); r.u[3] = pk2(b.z, b.w);
    return r.v;
}
__device__ __forceinline__ unsigned f2u(float f) {
    union { float f; unsigned u; } v; v.f = f; return v.u;
}
__device__ __forceinline__ float u2f(unsigned u) {
    union { unsigned u; float f; } v; v.u = u; return v.f;
}

// ---- init: one wave per code (R14 layout) ----
__global__ __launch_bounds__(64) void vq_init(const float* __restrict__ emb,
                                              float* __restrict__ ws) {
    const int code = blockIdx.x, l = threadIdx.x;
    const float* e = emb + code * D;
    if (code == 0 && l == 0) ws[0] = 0.0f;
    float a = e[l];
    float b = (l < D - 64) ? e[64 + l] : 0.0f;
    float p = fmaf(a, a, b * b);
#pragma unroll
    for (int off = 32; off; off >>= 1) p += __shfl_xor(p, off);   // all lanes: e2
    if (l == 0) ws[E2_OFF + code] = p;

    // cb granules: 16 per code, written by lanes 0..15 (8 shorts each)
    if (l < 16) {
        const int s = l >> 2, q = l & 3;
        short8 v;
#pragma unroll
        for (int j = 0; j < 8; ++j) {
            int k = s * 32 + q * 8 + j;
            v[j] = (k < D) ? (short)f2bf(e[k]) : (short)0;
        }
        if (l == 12) v[4] = (short)f2bf(-0.5f * p);   // k=100 slot: -e2/2
        const int chunk = code >> 5, ci = code & 31;
        const int tt = ci >> 4, lr = ci & 15;
        unsigned short* cb = (unsigned short*)((char*)ws + CB_OFF);
        // short offset = chunk*4096 + granule*8, granule = (s*2+tt)*64 + q*16 + lr
        *(short8*)(cb + chunk * 4096 + ((s * 2 + tt) * 64 + q * 16 + lr) * 8) = v;
    }
}

// ---- main: 4 waves/block, 64 rows/wave (M=4), B via 4-chunk double-buffered LDS ----
__global__ __launch_bounds__(256, 2) void vq_main(const float* __restrict__ x,
                                                  const float* __restrict__ emb,
                                                  float* __restrict__ ws,
                                                  float* __restrict__ out) {
    __shared__ uint4  bbuf[2][2048];  // 2 x 32 KB: four chunks per buffer
    __shared__ int    widx[256];
    __shared__ float  wsum[4];

    const int tid = threadIdx.x, wave = tid >> 6, lane = tid & 63;
    const int quad = lane >> 4, lr = lane & 15;
    const int lrc = 15 - lr;                          // code-complement lane part
    const long brow = (long)blockIdx.x * 256;
    const long wrow = brow + wave * 64;

    // ---- A: 28 independent scattered loads (batched), then convert ----
    float4 av[4][7];
#pragma unroll
    for (int m = 0; m < 4; ++m) {
        const float* xr = x + (wrow + m * 16 + lr) * D + quad * 8;
        av[m][0] = *(const float4*)(xr);
        av[m][1] = *(const float4*)(xr + 4);
        av[m][2] = *(const float4*)(xr + 32);
        av[m][3] = *(const float4*)(xr + 36);
        av[m][4] = *(const float4*)(xr + 64);
        av[m][5] = *(const float4*)(xr + 68);
        av[m][6] = *(const float4*)(x + (wrow + m * 16 + lr) * D + 96);  // same addr all quads
    }

    // ---- B chunks 0..3 staging (8 coalesced uint4/thread; in flight with A) ----
    const uint4* __restrict__ cbg = (const uint4*)((const char*)ws + CB_OFF);
    uint4 st[8];
#pragma unroll
    for (int k = 0; k < 8; ++k) st[k] = cbg[k * 256 + tid];

    // ---- convert A -> fragments + fp32 norms; k=100 carries 1.0 (quad 0) ----
    short8 A[4][4];
    float  xnorm[4];
    const float4 one0 = make_float4(quad == 0 ? 1.f : 0.f, 0.f, 0.f, 0.f);
#pragma unroll
    for (int m = 0; m < 4; ++m) {
        float4 z = av[m][6];
        if (quad != 0) z = make_float4(0.f, 0.f, 0.f, 0.f);   // tail only in quad 0
        float nrm = 0.f;
#pragma unroll
        for (int i = 0; i < 6; ++i) {
            float4 f = av[m][i];
            nrm = fmaf(f.x, f.x, nrm); nrm = fmaf(f.y, f.y, nrm);
            nrm = fmaf(f.z, f.z, nrm); nrm = fmaf(f.w, f.w, nrm);
        }
        nrm = fmaf(z.x, z.x, nrm); nrm = fmaf(z.y, z.y, nrm);
        nrm = fmaf(z.z, z.z, nrm); nrm = fmaf(z.w, z.w, nrm);
        A[m][0] = pack8(av[m][0], av[m][1]);
        A[m][1] = pack8(av[m][2], av[m][3]);
        A[m][2] = pack8(av[m][4], av[m][5]);
        A[m][3] = pack8(z, one0);                     // k=100 -> 1.0 (quad 0)
        nrm += __shfl_xor(nrm, 16);
        nrm += __shfl_xor(nrm, 32);
        xnorm[m] = nrm;
    }

#pragma unroll
    for (int k = 0; k < 8; ++k) bbuf[0][k * 256 + tid] = st[k];
    __syncthreads();

    // packed running max: acc with 9 LSBs = 511-code (argmax acc == argmin score)
    float runpk[4][4];
#pragma unroll
    for (int m = 0; m < 4; ++m)
#pragma unroll
        for (int r = 0; r < 4; ++r) runpk[m][r] = -FLT_MAX;

#pragma unroll 1
    for (int j = 0; j < 4; ++j) {
        const int p = j & 1;
        if (j < 3) {                      // prefetch next 4 chunks into regs
#pragma unroll
            for (int k = 0; k < 8; ++k) st[k] = cbg[(j + 1) * 2048 + k * 256 + tid];
        }

#pragma unroll
        for (int cc = 0; cc < 4; ++cc) {
            const int c = j * 4 + cc;
            // B fragments: lane-linear ds_read_b128, conflict-free
            const short8* __restrict__ bl = (const short8*)&bbuf[p][cc * 512];
            short8 B[2][4];
#pragma unroll
            for (int s = 0; s < 4; ++s) {
                B[0][s] = bl[(s * 2 + 0) * 64 + lane];
                B[1][s] = bl[(s * 2 + 1) * 64 + lane];
            }

            f32x4 acc[4][2];
#pragma unroll
            for (int m = 0; m < 4; ++m) {
                acc[m][0] = (f32x4){0.f, 0.f, 0.f, 0.f};
                acc[m][1] = (f32x4){0.f, 0.f, 0.f, 0.f};
            }
#pragma unroll
            for (int s = 0; s < 4; ++s)
#pragma unroll
                for (int m = 0; m < 4; ++m) {
                    acc[m][0] = __builtin_amdgcn_mfma_f32_16x16x32_bf16(A[m][s], B[0][s], acc[m][0], 0, 0, 0);
                    acc[m][1] = __builtin_amdgcn_mfma_f32_16x16x32_bf16(A[m][s], B[1][s], acc[m][1], 0, 0, 0);
                }

            // fold: pack (511-code) into 9 LSBs, running float max (and_or + max3)
            const int ib0 = (31 - (c * 2 + 0)) * 16 + lrc;
            const int ib1 = (31 - (c * 2 + 1)) * 16 + lrc;
#pragma unroll
            for (int m = 0; m < 4; ++m)
#pragma unroll
                for (int r = 0; r < 4; ++r) {
                    float p0 = u2f((f2u(acc[m][0][r]) & ~511u) | (unsigned)ib0);
                    float p1 = u2f((f2u(acc[m][1][r]) & ~511u) | (unsigned)ib1);
                    runpk[m][r] = fmaxf(runpk[m][r], fmaxf(p0, p1));
                }
        }

        if (j < 3) {
#pragma unroll
            for (int k = 0; k < 8; ++k) bbuf[p ^ 1][k * 256 + tid] = st[k];
        }
        __syncthreads();
    }

    // ---- per-row argmax across the 16 columns: pure float max-reduce ----
    float lsum = 0.0f;
#pragma unroll
    for (int m = 0; m < 4; ++m)
#pragma unroll
        for (int r = 0; r < 4; ++r) {
            float s = runpk[m][r];
#pragma unroll
            for (int off = 8; off >= 1; off >>= 1)
                s = fmaxf(s, __shfl_xor(s, off));
            if (lr == quad * 4 + r) {                  // writer lane for this row
                unsigned u = f2u(s);
                int code = 511 - (int)(u & 511u);
                lsum += fmaf(-2.0f, s, xnorm[m]);      // ||x||^2 - 2*(<x,e> - e2/2)
                widx[wave * 64 + m * 16 + quad * 4 + r] = code;
            }
        }
#pragma unroll
    for (int off = 32; off >= 1; off >>= 1) lsum += __shfl_xor(lsum, off);
    if (lane == 0) wsum[wave] = lsum;
    __syncthreads();                                   // wsum + widx visible
    if (tid == 0) atomicAdd(ws, wsum[0] + wsum[1] + wsum[2] + wsum[3]);

    // ---- coalesced epilogue: 6400 float4 = 256 rows x 25, batched 5-deep ----
    const float4* __restrict__ ef = (const float4*)emb;   // 25 float4 per row, exact
    float4* __restrict__ og = (float4*)(out + brow * D);
#pragma unroll
    for (int i = 0; i < 25; i += 5) {
        float4 q[5];
        int    gi[5];
#pragma unroll
        for (int u = 0; u < 5; ++u) {
            int g = (i + u) * 256 + tid;
            int row = g / 25;                 // const-divisor magic div
            int c4  = g - row * 25;
            gi[u] = g;
            q[u]  = ef[(long)widx[row] * 25 + c4];
        }
#pragma unroll
        for (int u = 0; u < 5; ++u) og[gi[u]] = q[u];
    }
}

// ---- finalize ----
__global__ void vq_final(const float* __restrict__ ws, float* __restrict__ out) {
    float mse = ws[0] / (float)((long)N_ROWS * D);
    out[(long)N_ROWS * D]     = mse;
    out[(long)N_ROWS * D + 1] = 0.25f * mse;
}

extern "C" void kernel_launch(void* const* d_in, const int* in_sizes, int n_in,
                              void* d_out, int out_size, void* d_ws, size_t ws_size,
                              hipStream_t stream) {
    const float* x   = (const float*)d_in[0];
    const float* emb = (const float*)d_in[1];
    float* out = (float*)d_out;
    float* ws  = (float*)d_ws;

    vq_init<<<KCODES, 64, 0, stream>>>(emb, ws);
    vq_main<<<N_ROWS / 256, 256, 0, stream>>>(x, emb, ws, out);
    vq_final<<<1, 1, 0, stream>>>(ws, out);
}

// Round 15
// 214.329 us; speedup vs baseline: 1.4686x; 1.1156x over previous
//
#include <hip/hip_runtime.h>
#include <hip/hip_bf16.h>
#include <cfloat>

// VQ-VAE vector quantizer.  N=262144 rows x D=100, K=512 codes.
// out[0..N*D-1] = quantized (fp32-exact gather); out[N*D]=mse; out[N*D+1]=0.25*mse.
//
// R20 = R14 verbatim (best-known, vq_main 86us) -- declared practical floor.
//  R19 (4-chunk rounds) and R18 (wave-private dbuf) both spilled (WRITE 172MB/
//  239MB vs 102MB clean): the register allocator will not hold the longer
//  live ranges, and scratch costs more than the ~2us barrier savings.
//  15-experiment ledger: only issue-work reduction (R14 fold, -14us, 1:1) and
//  round-halving (R11, -4us) ever converted; occupancy x3, barrier-free x3,
//  fp8 LDS-bytes, 32x32 MFMA, chain interleave, global_load_lds: all null or
//  negative.  No classical roofline in the counters (HBM 23%, MFMA 16%,
//  VALU 22%); binding constraint is the per-wave issue/stall structure.
//
// ws: ws_f[0] = loss accum; ws_f[16..528) = e2[k] (fp32, reference);
//     bytes [4096..4096+131072): bf16 cb; chunk c granule layout (16B granules):
//     granule g = (s*2+tt)*64 + quad*16 + lr  holds code (c*32+tt*16+lr),
//     k = s*32+quad*8+{0..7}; k=100 slot holds bf16(-e2/2); other k>=101 zero.

#define N_ROWS (64 * 64 * 64)
#define D 100
#define KCODES 512
#define CB_OFF 4096
#define E2_OFF 16

typedef __attribute__((ext_vector_type(8))) short short8;
typedef __attribute__((ext_vector_type(4))) float f32x4;

__device__ __forceinline__ unsigned short f2bf(float f) {
    union { float f; unsigned u; } v; v.f = f;
    unsigned r = v.u + 0x7FFF + ((v.u >> 16) & 1);   // RNE
    return (unsigned short)(r >> 16);
}
__device__ __forceinline__ unsigned pk2(float a, float b) {   // packed bf16 cvt (RNE)
    union { __hip_bfloat162 h; unsigned u; } c;
    c.h = __float22bfloat162_rn(make_float2(a, b));
    return c.u;
}
__device__ __forceinline__ short8 pack8(const float4& a, const float4& b) {
    union { unsigned u[4]; short8 v; } r;
    r.u[0] = pk2(a.x, a.y); r.u[1] = pk2(a.z, a.w);
    r.u[2] = pk2(b.x, b.y); r.u[3] = pk2(b.z, b.w);
    return r.v;
}
__device__ __forceinline__ unsigned f2u(float f) {
    union { float f; unsigned u; } v; v.f = f; return v.u;
}
__device__ __forceinline__ float u2f(unsigned u) {
    union { unsigned u; float f; } v; v.u = u; return v.f;
}

// ---- init: one wave per code ----
__global__ __launch_bounds__(64) void vq_init(const float* __restrict__ emb,
                                              float* __restrict__ ws) {
    const int code = blockIdx.x, l = threadIdx.x;
    const float* e = emb + code * D;
    if (code == 0 && l == 0) ws[0] = 0.0f;
    float a = e[l];
    float b = (l < D - 64) ? e[64 + l] : 0.0f;
    float p = fmaf(a, a, b * b);
#pragma unroll
    for (int off = 32; off; off >>= 1) p += __shfl_xor(p, off);   // all lanes: e2
    if (l == 0) ws[E2_OFF + code] = p;

    // cb granules: 16 per code, written by lanes 0..15 (8 shorts each)
    if (l < 16) {
        const int s = l >> 2, q = l & 3;
        short8 v;
#pragma unroll
        for (int j = 0; j < 8; ++j) {
            int k = s * 32 + q * 8 + j;
            v[j] = (k < D) ? (short)f2bf(e[k]) : (short)0;
        }
        if (l == 12) v[4] = (short)f2bf(-0.5f * p);   // k=100 slot: -e2/2
        const int chunk = code >> 5, ci = code & 31;
        const int tt = ci >> 4, lr = ci & 15;
        unsigned short* cb = (unsigned short*)((char*)ws + CB_OFF);
        // short offset = chunk*4096 + granule*8, granule = (s*2+tt)*64 + q*16 + lr
        *(short8*)(cb + chunk * 4096 + ((s * 2 + tt) * 64 + q * 16 + lr) * 8) = v;
    }
}

// ---- main: 4 waves/block, 64 rows/wave (M=4), B via 2-chunk double-buffered LDS ----
__global__ __launch_bounds__(256, 2) void vq_main(const float* __restrict__ x,
                                                  const float* __restrict__ emb,
                                                  float* __restrict__ ws,
                                                  float* __restrict__ out) {
    __shared__ uint4  bbuf[2][1024];  // 2 x 16 KB: two chunks per buffer
    __shared__ int    widx[256];
    __shared__ float  wsum[4];

    const int tid = threadIdx.x, wave = tid >> 6, lane = tid & 63;
    const int quad = lane >> 4, lr = lane & 15;
    const int lrc = 15 - lr;                          // code-complement lane part
    const long brow = (long)blockIdx.x * 256;
    const long wrow = brow + wave * 64;

    // ---- A: 28 independent scattered loads (batched), then convert ----
    float4 av[4][7];
#pragma unroll
    for (int m = 0; m < 4; ++m) {
        const float* xr = x + (wrow + m * 16 + lr) * D + quad * 8;
        av[m][0] = *(const float4*)(xr);
        av[m][1] = *(const float4*)(xr + 4);
        av[m][2] = *(const float4*)(xr + 32);
        av[m][3] = *(const float4*)(xr + 36);
        av[m][4] = *(const float4*)(xr + 64);
        av[m][5] = *(const float4*)(xr + 68);
        av[m][6] = *(const float4*)(x + (wrow + m * 16 + lr) * D + 96);  // same addr all quads
    }

    // ---- B chunks 0,1 staging (issued while A loads are in flight) ----
    const uint4* __restrict__ cbg = (const uint4*)((const char*)ws + CB_OFF);
    uint4 st0 = cbg[wave * 128 + lane];
    uint4 st1 = cbg[wave * 128 + 64 + lane];
    uint4 st2 = cbg[512 + wave * 128 + lane];
    uint4 st3 = cbg[512 + wave * 128 + 64 + lane];

    // ---- convert A -> fragments + fp32 norms; k=100 carries 1.0 (quad 0) ----
    short8 A[4][4];
    float  xnorm[4];
    const float4 one0 = make_float4(quad == 0 ? 1.f : 0.f, 0.f, 0.f, 0.f);
#pragma unroll
    for (int m = 0; m < 4; ++m) {
        float4 z = av[m][6];
        if (quad != 0) z = make_float4(0.f, 0.f, 0.f, 0.f);   // tail only in quad 0
        float nrm = 0.f;
#pragma unroll
        for (int i = 0; i < 6; ++i) {
            float4 f = av[m][i];
            nrm = fmaf(f.x, f.x, nrm); nrm = fmaf(f.y, f.y, nrm);
            nrm = fmaf(f.z, f.z, nrm); nrm = fmaf(f.w, f.w, nrm);
        }
        nrm = fmaf(z.x, z.x, nrm); nrm = fmaf(z.y, z.y, nrm);
        nrm = fmaf(z.z, z.z, nrm); nrm = fmaf(z.w, z.w, nrm);
        A[m][0] = pack8(av[m][0], av[m][1]);
        A[m][1] = pack8(av[m][2], av[m][3]);
        A[m][2] = pack8(av[m][4], av[m][5]);
        A[m][3] = pack8(z, one0);                     // k=100 -> 1.0 (quad 0)
        nrm += __shfl_xor(nrm, 16);
        nrm += __shfl_xor(nrm, 32);
        xnorm[m] = nrm;
    }

    bbuf[0][wave * 128 + lane]             = st0;
    bbuf[0][wave * 128 + 64 + lane]        = st1;
    bbuf[0][512 + wave * 128 + lane]       = st2;
    bbuf[0][512 + wave * 128 + 64 + lane]  = st3;
    __syncthreads();

    // packed running max: acc with 9 LSBs = 511-code (argmax acc == argmin score)
    float runpk[4][4];
#pragma unroll
    for (int m = 0; m < 4; ++m)
#pragma unroll
        for (int r = 0; r < 4; ++r) runpk[m][r] = -FLT_MAX;

#pragma unroll 1
    for (int j = 0; j < 8; ++j) {
        const int p = j & 1;
        uint4 n0, n1, n2, n3;
        if (j < 7) {                      // prefetch next 2 chunks into regs
            n0 = cbg[(j + 1) * 1024 + wave * 128 + lane];
            n1 = cbg[(j + 1) * 1024 + wave * 128 + 64 + lane];
            n2 = cbg[(j + 1) * 1024 + 512 + wave * 128 + lane];
            n3 = cbg[(j + 1) * 1024 + 512 + wave * 128 + 64 + lane];
        }

#pragma unroll
        for (int cc = 0; cc < 2; ++cc) {
            const int c = j * 2 + cc;
            // B fragments: lane-linear ds_read_b128, conflict-free
            const short8* __restrict__ bl = (const short8*)&bbuf[p][cc * 512];
            short8 B[2][4];
#pragma unroll
            for (int s = 0; s < 4; ++s) {
                B[0][s] = bl[(s * 2 + 0) * 64 + lane];
                B[1][s] = bl[(s * 2 + 1) * 64 + lane];
            }

            f32x4 acc[4][2];
#pragma unroll
            for (int m = 0; m < 4; ++m) {
                acc[m][0] = (f32x4){0.f, 0.f, 0.f, 0.f};
                acc[m][1] = (f32x4){0.f, 0.f, 0.f, 0.f};
            }
#pragma unroll
            for (int s = 0; s < 4; ++s)
#pragma unroll
                for (int m = 0; m < 4; ++m) {
                    acc[m][0] = __builtin_amdgcn_mfma_f32_16x16x32_bf16(A[m][s], B[0][s], acc[m][0], 0, 0, 0);
                    acc[m][1] = __builtin_amdgcn_mfma_f32_16x16x32_bf16(A[m][s], B[1][s], acc[m][1], 0, 0, 0);
                }

            // fold: pack (511-code) into 9 LSBs, running float max (v_and_or + max3)
            const int ib0 = (31 - (c * 2 + 0)) * 16 + lrc;
            const int ib1 = (31 - (c * 2 + 1)) * 16 + lrc;
#pragma unroll
            for (int m = 0; m < 4; ++m)
#pragma unroll
                for (int r = 0; r < 4; ++r) {
                    float p0 = u2f((f2u(acc[m][0][r]) & ~511u) | (unsigned)ib0);
                    float p1 = u2f((f2u(acc[m][1][r]) & ~511u) | (unsigned)ib1);
                    runpk[m][r] = fmaxf(runpk[m][r], fmaxf(p0, p1));
                }
        }

        if (j < 7) {
            bbuf[p ^ 1][wave * 128 + lane]            = n0;
            bbuf[p ^ 1][wave * 128 + 64 + lane]       = n1;
            bbuf[p ^ 1][512 + wave * 128 + lane]      = n2;
            bbuf[p ^ 1][512 + wave * 128 + 64 + lane] = n3;
        }
        __syncthreads();
    }

    // ---- per-row argmax across the 16 columns: pure float max-reduce ----
    float lsum = 0.0f;
#pragma unroll
    for (int m = 0; m < 4; ++m)
#pragma unroll
        for (int r = 0; r < 4; ++r) {
            float s = runpk[m][r];
#pragma unroll
            for (int off = 8; off >= 1; off >>= 1)
                s = fmaxf(s, __shfl_xor(s, off));
            if (lr == quad * 4 + r) {                  // writer lane for this row
                unsigned u = f2u(s);
                int code = 511 - (int)(u & 511u);
                lsum += fmaf(-2.0f, s, xnorm[m]);      // ||x||^2 - 2*(<x,e> - e2/2)
                widx[wave * 64 + m * 16 + quad * 4 + r] = code;
            }
        }
#pragma unroll
    for (int off = 32; off >= 1; off >>= 1) lsum += __shfl_xor(lsum, off);
    if (lane == 0) wsum[wave] = lsum;
    __syncthreads();                                   // wsum + widx visible
    if (tid == 0) atomicAdd(ws, wsum[0] + wsum[1] + wsum[2] + wsum[3]);

    // ---- coalesced epilogue: 6400 float4 = 256 rows x 25, batched 5-deep ----
    const float4* __restrict__ ef = (const float4*)emb;   // 25 float4 per row, exact
    float4* __restrict__ og = (float4*)(out + brow * D);
#pragma unroll
    for (int i = 0; i < 25; i += 5) {
        float4 q[5];
        int    gi[5];
#pragma unroll
        for (int u = 0; u < 5; ++u) {
            int g = (i + u) * 256 + tid;
            int row = g / 25;                 // const-divisor magic div
            int c4  = g - row * 25;
            gi[u] = g;
            q[u]  = ef[(long)widx[row] * 25 + c4];
        }
#pragma unroll
        for (int u = 0; u < 5; ++u) og[gi[u]] = q[u];
    }
}

// ---- finalize ----
__global__ void vq_final(const float* __restrict__ ws, float* __restrict__ out) {
    float mse = ws[0] / (float)((long)N_ROWS * D);
    out[(long)N_ROWS * D]     = mse;
    out[(long)N_ROWS * D + 1] = 0.25f * mse;
}

extern "C" void kernel_launch(void* const* d_in, const int* in_sizes, int n_in,
                              void* d_out, int out_size, void* d_ws, size_t ws_size,
                              hipStream_t stream) {
    const float* x   = (const float*)d_in[0];
    const float* emb = (const float*)d_in[1];
    float* out = (float*)d_out;
    float* ws  = (float*)d_ws;

    vq_init<<<KCODES, 64, 0, stream>>>(emb, ws);
    vq_main<<<N_ROWS / 256, 256, 0, stream>>>(x, emb, ws, out);
    vq_final<<<1, 1, 0, stream>>>(ws, out);
}